// Round 2
// baseline (238.520 us; speedup 1.0000x reference)
//
#include <hip/hip_runtime.h>
#include <hip/hip_bf16.h>
#include <hip/hip_fp8.h>
#include <math.h>

#define N 8192
#define D 512
#define BM 128
#define BK 64
#define NSTRIP 64                       // N / BM
#define S_BLOCKS (NSTRIP * NSTRIP)      // 4096 S tiles
#define TRI (NSTRIP * (NSTRIP + 1) / 2) // 2080
#define G_BLOCKS (2 * TRI)              // 4160 Gram tiles
#define SG_BLOCKS (S_BLOCKS + G_BLOCKS) // 8256

typedef float f32x16 __attribute__((ext_vector_type(16)));
typedef int i32x4 __attribute__((ext_vector_type(4)));
typedef int i32x8 __attribute__((ext_vector_type(8)));

__device__ inline void gload_lds16(const void* g, void* l) {
  __builtin_amdgcn_global_load_lds(
      (const __attribute__((address_space(1))) void*)g,
      (__attribute__((address_space(3))) void*)l, 16, 0, 0);
}

// ---------------- normalize to fp8 e4m3 + exact fp32 diagonal + zero out ----------------
__global__ __launch_bounds__(256) void norm_kernel(
    const float* __restrict__ z1, const float* __restrict__ z2,
    unsigned char* __restrict__ q1, unsigned char* __restrict__ q2,
    float* __restrict__ diag, float* __restrict__ out) {
  int row = blockIdx.x;
  int t = threadIdx.x;
  if (row == 0 && t == 0) out[0] = 0.0f; // atomic target for combine (stream-ordered)
  const float2* a = (const float2*)(z1 + (size_t)row * D);
  const float2* b = (const float2*)(z2 + (size_t)row * D);
  float2 xa = a[t];
  float2 xb = b[t];
  float ss1 = xa.x * xa.x + xa.y * xa.y;
  float ss2 = xb.x * xb.x + xb.y * xb.y;
  float dd = xa.x * xb.x + xa.y * xb.y;
#pragma unroll
  for (int off = 1; off < 64; off <<= 1) {
    ss1 += __shfl_xor(ss1, off);
    ss2 += __shfl_xor(ss2, off);
    dd  += __shfl_xor(dd,  off);
  }
  __shared__ float red[3][4];
  int wv = t >> 6;
  if ((t & 63) == 0) { red[0][wv] = ss1; red[1][wv] = ss2; red[2][wv] = dd; }
  __syncthreads();
  ss1 = red[0][0] + red[0][1] + red[0][2] + red[0][3];
  ss2 = red[1][0] + red[1][1] + red[1][2] + red[1][3];
  dd  = red[2][0] + red[2][1] + red[2][2] + red[2][3];
  float i1 = 1.0f / fmaxf(sqrtf(ss1), 1e-12f);
  float i2 = 1.0f / fmaxf(sqrtf(ss2), 1e-12f);
  __hip_fp8_e4m3 c1a(xa.x * i1), c1b(xa.y * i1); // OCP e4m3fn
  __hip_fp8_e4m3 c2a(xb.x * i2), c2b(xb.y * i2);
  uchar2 u1; u1.x = c1a.__x; u1.y = c1b.__x;
  uchar2 u2; u2.x = c2a.__x; u2.y = c2b.__x;
  ((uchar2*)q1)[(size_t)row * 256 + t] = u1;
  ((uchar2*)q2)[(size_t)row * 256 + t] = u2;
  if (t == 0) diag[row] = dd * i1 * i2;
}

// ---------------- staging: one 64B k-chunk of A and B into ring buffer --------------
// Per-thread base pointers precomputed (src swizzle folded in); k0 is wave-uniform.
// LDS slot s holds chunk (s ^ ((row>>1)&3)) of its row.
__device__ __forceinline__ void stage_pair(
    const unsigned char* pA, const unsigned char* pB,
    unsigned char (*Ab)[BM * BK], unsigned char (*Bb)[BM * BK],
    int ldst, int chunk) {
  int buf = chunk & 3;
  int k0 = chunk * BK;
  gload_lds16(pA + k0, &Ab[buf][ldst]);
  gload_lds16(pA + 64 * D + k0, &Ab[buf][4096 + ldst]);
  gload_lds16(pB + k0, &Bb[buf][ldst]);
  gload_lds16(pB + 64 * D + k0, &Bb[buf][4096 + ldst]);
}

// ---------------- 128x128 MX fp8 tile, quad-buffered BK=128 super-rounds ----------------
// 4 rounds, each: barrier (drains chunks staged one full round ago), stage next 2
// chunks, 16 ds_read_b128, 8 mfma_scale_32x32x64 (~550cy) -> staging latency covered.
// Unit E8M0 scales (0x7F) == exact fp8 product at 2.3x the non-scaled pipe rate.
__device__ __forceinline__ void mm_tile_mx(
    const unsigned char* __restrict__ X, const unsigned char* __restrict__ Y,
    int r0, int c0, unsigned char (*Ab)[BM * BK], unsigned char (*Bb)[BM * BK],
    f32x16 (&acc)[2][2], int t, int l31, int h, int rw, int cw) {
#pragma unroll
  for (int i = 0; i < 2; i++)
#pragma unroll
    for (int j = 0; j < 2; j++)
#pragma unroll
      for (int r = 0; r < 16; r++) acc[i][j][r] = 0.0f;

  // staging pointers: slot s = it*256+t -> row = s>>2 (+64*it), src = (t&3)^((t>>3)&3)
  int srow = t >> 2;
  int ssrc = (t & 3) ^ ((t >> 3) & 3);
  const unsigned char* pA = X + (size_t)(r0 + srow) * D + ssrc * 16;
  const unsigned char* pB = Y + (size_t)(c0 + srow) * D + ssrc * 16;
  int ldst = t * 16;

  // kc-invariant fragment LDS offsets (within an 8KB buffer):
  // lane (l31,h) of sub-block reads chunks {2h,2h+1} of its row, through the swizzle.
  int offA[2][2], offB[2][2];
#pragma unroll
  for (int i = 0; i < 2; i++) {
    int row = rw * 64 + i * 32 + l31;
    int sw = (row >> 1) & 3;
    offA[i][0] = row * 64 + (((h << 1) | 0) ^ sw) * 16;
    offA[i][1] = row * 64 + (((h << 1) | 1) ^ sw) * 16;
  }
#pragma unroll
  for (int j = 0; j < 2; j++) {
    int row = cw * 64 + j * 32 + l31;
    int sw = (row >> 1) & 3;
    offB[j][0] = row * 64 + (((h << 1) | 0) ^ sw) * 16;
    offB[j][1] = row * 64 + (((h << 1) | 1) ^ sw) * 16;
  }

  stage_pair(pA, pB, Ab, Bb, ldst, 0);
  stage_pair(pA, pB, Ab, Bb, ldst, 1);

#pragma unroll
  for (int p = 0; p < 4; p++) {
    __syncthreads(); // drains stages for chunks 2p,2p+1 (issued one round ago)
    if (p < 3) {
      stage_pair(pA, pB, Ab, Bb, ldst, 2 * p + 2);
      stage_pair(pA, pB, Ab, Bb, ldst, 2 * p + 3);
    }
    const unsigned char* A0 = Ab[(2 * p) & 3];
    const unsigned char* B0 = Bb[(2 * p) & 3];
    const unsigned char* A1 = Ab[(2 * p + 1) & 3];
    const unsigned char* B1 = Bb[(2 * p + 1) & 3];
    i32x8 a0[2], b0[2], a1[2], b1[2];
#pragma unroll
    for (int i = 0; i < 2; i++) {
      i32x4 lo = *(const i32x4*)(A0 + offA[i][0]);
      i32x4 hi = *(const i32x4*)(A0 + offA[i][1]);
      a0[i] = __builtin_shufflevector(lo, hi, 0, 1, 2, 3, 4, 5, 6, 7);
      lo = *(const i32x4*)(A1 + offA[i][0]);
      hi = *(const i32x4*)(A1 + offA[i][1]);
      a1[i] = __builtin_shufflevector(lo, hi, 0, 1, 2, 3, 4, 5, 6, 7);
    }
#pragma unroll
    for (int j = 0; j < 2; j++) {
      i32x4 lo = *(const i32x4*)(B0 + offB[j][0]);
      i32x4 hi = *(const i32x4*)(B0 + offB[j][1]);
      b0[j] = __builtin_shufflevector(lo, hi, 0, 1, 2, 3, 4, 5, 6, 7);
      lo = *(const i32x4*)(B1 + offB[j][0]);
      hi = *(const i32x4*)(B1 + offB[j][1]);
      b1[j] = __builtin_shufflevector(lo, hi, 0, 1, 2, 3, 4, 5, 6, 7);
    }
    __builtin_amdgcn_s_setprio(1);
#pragma unroll
    for (int i = 0; i < 2; i++)
#pragma unroll
      for (int j = 0; j < 2; j++)
        acc[i][j] = __builtin_amdgcn_mfma_scale_f32_32x32x64_f8f6f4(
            a0[i], b0[j], acc[i][j], 0, 0, 0, 0x7F7F7F7F, 0, 0x7F7F7F7F);
#pragma unroll
    for (int i = 0; i < 2; i++)
#pragma unroll
      for (int j = 0; j < 2; j++)
        acc[i][j] = __builtin_amdgcn_mfma_scale_f32_32x32x64_f8f6f4(
            a1[i], b1[j], acc[i][j], 0, 0, 0, 0x7F7F7F7F, 0, 0x7F7F7F7F);
    __builtin_amdgcn_s_setprio(0);
  }
}

// ---------------- fused S + G pass: one 128x128 tile per block ----------------
// 32x32 C/D layout: col = lane&31, row = (reg&3) + 8*(reg>>2) + 4*(lane>>5)
__global__ __launch_bounds__(256, 2) void sg_kernel(
    const unsigned char* __restrict__ q1, const unsigned char* __restrict__ q2,
    float* __restrict__ rowS, float* __restrict__ colS,
    float* __restrict__ partG) {
  __shared__ unsigned char Ab[4][BM * BK]; // 32 KB ring (A)
  __shared__ unsigned char Bb[4][BM * BK]; // 32 KB ring (B)
  // reductions alias the (dead after k-loop) A ring; guarded by a barrier.
  float (*redA)[BM] = reinterpret_cast<float (*)[BM]>(&Ab[0][0]);
  float (*redB)[BM] = reinterpret_cast<float (*)[BM]>(&Ab[0][0] + 1024);

  int bx = blockIdx.x; // natural dispatch order (R1's XCD chunking raised FETCH)
  int t = threadIdx.x;
  int lane = t & 63;
  int wave = t >> 6;
  int l31 = lane & 31;
  int h = lane >> 5; // k-half for frags / row-half for C/D
  int rw = wave >> 1;
  int cw = wave & 1;
  const float scale = 1.4426950408889634f / 0.04f; // log2(e)/T

  bool smode = bx < S_BLOCKS;
  const unsigned char* X;
  const unsigned char* Y;
  int r0, c0, ga = 0, gb = 0, gg = 0;
  bool diagb = false;
  if (smode) {
    r0 = (bx >> 6) * BM;
    c0 = (bx & 63) * BM;
    X = q1; Y = q2;
  } else {
    int gx = bx - S_BLOCKS;
    gg = (gx >= TRI) ? 1 : 0;
    int tri = gx - gg * TRI;
    int a = (int)((sqrtf(8.0f * (float)tri + 1.0f) - 1.0f) * 0.5f);
    while ((a + 1) * (a + 2) / 2 <= tri) a++;
    while (a * (a + 1) / 2 > tri) a--;
    int b = tri - a * (a + 1) / 2; // b <= a
    ga = a; gb = b;
    X = gg ? q2 : q1; Y = X;
    r0 = a * BM;
    c0 = b * BM;
    diagb = (a == b);
  }

  f32x16 acc[2][2];
  mm_tile_mx(X, Y, r0, c0, Ab, Bb, acc, t, l31, h, rw, cw);

  __syncthreads(); // all LDS reads done before red* (aliases Ab) is written

  if (smode) {
    // ---- row + col sums of exp2(scale*g); fixed reference (fits fp32) ----
    float csum[2] = {0.0f, 0.0f};
#pragma unroll
    for (int i = 0; i < 2; i++) {
      float rsum[16];
#pragma unroll
      for (int reg = 0; reg < 16; reg++) rsum[reg] = 0.0f;
#pragma unroll
      for (int j = 0; j < 2; j++)
#pragma unroll
        for (int reg = 0; reg < 16; reg++) {
          float e = __builtin_amdgcn_exp2f(acc[i][j][reg] * scale);
          rsum[reg] += e;
          csum[j] += e;
        }
      // row-sum: reduce across the 32 lanes of this k/row-half (bit5 preserved)
#pragma unroll
      for (int reg = 0; reg < 16; reg++) {
#pragma unroll
        for (int off = 1; off < 32; off <<= 1) rsum[reg] += __shfl_xor(rsum[reg], off);
      }
      if (l31 == 0) {
#pragma unroll
        for (int reg = 0; reg < 16; reg++) {
          int rloc = (reg & 3) + 8 * (reg >> 2) + 4 * h;
          redB[cw][rw * 64 + i * 32 + rloc] = rsum[reg];
        }
      }
    }
    // col-sum: add the other row-half, then one lane-half writes
#pragma unroll
    for (int j = 0; j < 2; j++) {
      csum[j] += __shfl_xor(csum[j], 32);
      if (h == 0) redA[rw][cw * 64 + j * 32 + l31] = csum[j];
    }
    __syncthreads();
    if (t < BM) {
      colS[(size_t)(r0 >> 7) * N + c0 + t] = redA[0][t] + redA[1][t];
      rowS[(size_t)(c0 >> 7) * N + r0 + t] = redB[0][t] + redB[1][t];
    }
  } else {
    // ---- Gram: row max (strip a), diag-masked; col max = row max of strip b ----
#pragma unroll
    for (int i = 0; i < 2; i++) {
      float rmax[16];
#pragma unroll
      for (int reg = 0; reg < 16; reg++) {
        int rloc = (reg & 3) + 8 * (reg >> 2) + 4 * h;
        int rr = rw * 64 + i * 32 + rloc;
        float v = -3.0e38f;
#pragma unroll
        for (int j = 0; j < 2; j++) {
          float x = acc[i][j][reg];
          int cc = cw * 64 + j * 32 + l31;
          if (diagb && cc == rr) x = -3.0e38f;
          v = fmaxf(v, x);
        }
        rmax[reg] = v;
      }
#pragma unroll
      for (int reg = 0; reg < 16; reg++) {
#pragma unroll
        for (int off = 1; off < 32; off <<= 1) rmax[reg] = fmaxf(rmax[reg], __shfl_xor(rmax[reg], off));
      }
      if (l31 == 0) {
#pragma unroll
        for (int reg = 0; reg < 16; reg++) {
          int rloc = (reg & 3) + 8 * (reg >> 2) + 4 * h;
          redA[cw][rw * 64 + i * 32 + rloc] = rmax[reg];
        }
      }
    }
    if (!diagb) {
#pragma unroll
      for (int j = 0; j < 2; j++) {
        float m = -3.0e38f;
#pragma unroll
        for (int i = 0; i < 2; i++)
#pragma unroll
          for (int reg = 0; reg < 16; reg++) m = fmaxf(m, acc[i][j][reg]);
        m = fmaxf(m, __shfl_xor(m, 32));
        if (h == 0) redB[rw][cw * 64 + j * 32 + l31] = m;
      }
    }
    __syncthreads();
    if (t < BM) {
      partG[((size_t)(gg * NSTRIP + gb)) * N + r0 + t] = fmaxf(redA[0][t], redA[1][t]);
      if (!diagb)
        partG[((size_t)(gg * NSTRIP + ga)) * N + c0 + t] = fmaxf(redB[0][t], redB[1][t]);
    }
  }
}

// ---------------- per-row combine of partials -> atomic scalar ----------------
// 128 blocks; each block: 64 rows, 4 strip-chunks in parallel (was 32 blocks with
// 256 serial loads/thread -> latency-bound).
__global__ __launch_bounds__(256) void combine_kernel(
    const float* __restrict__ diag,
    const float* __restrict__ rowS, const float* __restrict__ colS,
    const float* __restrict__ partG, float* __restrict__ out) {
  int t = threadIdx.x;
  int l = t & 63;
  int w = t >> 6;
  int i = blockIdx.x * 64 + l;

  float sR = 0.0f, sC = 0.0f, g1 = -3.0e38f, g2 = -3.0e38f;
#pragma unroll
  for (int s = 0; s < 16; s++) {
    int strip = w * 16 + s;
    sR += rowS[(size_t)strip * N + i];
    sC += colS[(size_t)strip * N + i];
    g1 = fmaxf(g1, partG[(size_t)strip * N + i]);
    g2 = fmaxf(g2, partG[(size_t)(NSTRIP + strip) * N + i]);
  }
  __shared__ float red[4][4][64];
  red[0][w][l] = sR; red[1][w][l] = sC; red[2][w][l] = g1; red[3][w][l] = g2;
  __syncthreads();
  if (w == 0) {
    sR = red[0][0][l] + red[0][1][l] + red[0][2][l] + red[0][3][l];
    sC = red[1][0][l] + red[1][1][l] + red[1][2][l] + red[1][3][l];
    g1 = fmaxf(fmaxf(red[2][0][l], red[2][1][l]), fmaxf(red[2][2][l], red[2][3][l]));
    g2 = fmaxf(fmaxf(red[3][0][l], red[3][1][l]), fmaxf(red[3][2][l], red[3][3][l]));
    float dv = diag[i] * 25.0f;
    float a12 = logf(sR) - dv;
    float a21 = logf(sC) - dv;
    float k1 = logf(sqrtf(fmaxf(2.0f - 2.0f * g1, 0.0f)) + 1e-9f);
    float k2 = logf(sqrtf(fmaxf(2.0f - 2.0f * g2, 0.0f)) + 1e-9f);
    float c = 0.5f * (a12 + a21) / (float)N - 0.1f * 0.5f * (k1 + k2) / (float)N;
#pragma unroll
    for (int off = 1; off < 64; off <<= 1) c += __shfl_xor(c, off);
    if (l == 0) atomicAdd(out, c); // device-scope, out zeroed by norm_kernel
  }
}

extern "C" void kernel_launch(void* const* d_in, const int* in_sizes, int n_in,
                              void* d_out, int out_size, void* d_ws, size_t ws_size,
                              hipStream_t stream) {
  const float* z1 = (const float*)d_in[0];
  const float* z2 = (const float*)d_in[1];
  char* w = (char*)d_ws;
  unsigned char* q1 = (unsigned char*)w; w += (size_t)N * D;
  unsigned char* q2 = (unsigned char*)w; w += (size_t)N * D;
  float* diag = (float*)w;   w += (size_t)N * sizeof(float);
  float* rowS = (float*)w;   w += (size_t)NSTRIP * N * sizeof(float);
  float* colS = (float*)w;   w += (size_t)NSTRIP * N * sizeof(float);
  float* partG = (float*)w;  w += (size_t)2 * NSTRIP * N * sizeof(float);
  float* out = (float*)d_out;

  norm_kernel<<<N, 256, 0, stream>>>(z1, z2, q1, q2, diag, out);
  sg_kernel<<<SG_BLOCKS, 256, 0, stream>>>(q1, q2, rowS, colS, partG);
  combine_kernel<<<N / 64, 256, 0, stream>>>(diag, rowS, colS, partG, out);
}

// Round 3
// 233.546 us; speedup vs baseline: 1.0213x; 1.0213x over previous
//
#include <hip/hip_runtime.h>
#include <hip/hip_bf16.h>
#include <hip/hip_fp8.h>
#include <math.h>

#define N 8192
#define D 512
#define BM 128
#define BK 64
#define NSTRIP 64                       // N / BM
#define S_BLOCKS (NSTRIP * NSTRIP)      // 4096 S tiles
#define TRI (NSTRIP * (NSTRIP + 1) / 2) // 2080
#define G_BLOCKS (2 * TRI)              // 4160 Gram tiles
#define SG_BLOCKS (S_BLOCKS + G_BLOCKS) // 8256

typedef float f32x16 __attribute__((ext_vector_type(16)));
typedef int i32x4 __attribute__((ext_vector_type(4)));
typedef int i32x8 __attribute__((ext_vector_type(8)));

__device__ inline void gload_lds16(const void* g, void* l) {
  __builtin_amdgcn_global_load_lds(
      (const __attribute__((address_space(1))) void*)g,
      (__attribute__((address_space(3))) void*)l, 16, 0, 0);
}

// ---------------- normalize to fp8 e4m3 + exact fp32 diagonal + zero out ----------------
// wave-per-row: 64 lanes x 8 floats = 512 = D; shuffle-only reduction, no barriers.
__global__ __launch_bounds__(256) void norm_kernel(
    const float* __restrict__ z1, const float* __restrict__ z2,
    unsigned char* __restrict__ q1, unsigned char* __restrict__ q2,
    float* __restrict__ diag, float* __restrict__ out) {
  int t = threadIdx.x;
  int lane = t & 63;
  int w = t >> 6;
  int row = blockIdx.x * 4 + w;
  if (blockIdx.x == 0 && t == 0) out[0] = 0.0f; // atomic target (stream-ordered)
  const float4* a = (const float4*)(z1 + (size_t)row * D);
  const float4* b = (const float4*)(z2 + (size_t)row * D);
  float4 xa0 = a[lane], xa1 = a[lane + 64];
  float4 xb0 = b[lane], xb1 = b[lane + 64];
  float ss1 = xa0.x * xa0.x + xa0.y * xa0.y + xa0.z * xa0.z + xa0.w * xa0.w +
              xa1.x * xa1.x + xa1.y * xa1.y + xa1.z * xa1.z + xa1.w * xa1.w;
  float ss2 = xb0.x * xb0.x + xb0.y * xb0.y + xb0.z * xb0.z + xb0.w * xb0.w +
              xb1.x * xb1.x + xb1.y * xb1.y + xb1.z * xb1.z + xb1.w * xb1.w;
  float dd = xa0.x * xb0.x + xa0.y * xb0.y + xa0.z * xb0.z + xa0.w * xb0.w +
             xa1.x * xb1.x + xa1.y * xb1.y + xa1.z * xb1.z + xa1.w * xb1.w;
#pragma unroll
  for (int off = 1; off < 64; off <<= 1) {
    ss1 += __shfl_xor(ss1, off);
    ss2 += __shfl_xor(ss2, off);
    dd  += __shfl_xor(dd,  off);
  }
  float i1 = 1.0f / fmaxf(sqrtf(ss1), 1e-12f);
  float i2 = 1.0f / fmaxf(sqrtf(ss2), 1e-12f);
  float fa[8] = {xa0.x, xa0.y, xa0.z, xa0.w, xa1.x, xa1.y, xa1.z, xa1.w};
  float fb[8] = {xb0.x, xb0.y, xb0.z, xb0.w, xb1.x, xb1.y, xb1.z, xb1.w};
  unsigned int u1[2], u2[2];
#pragma unroll
  for (int g = 0; g < 2; g++) {
    unsigned int v1 = 0, v2 = 0;
#pragma unroll
    for (int e = 0; e < 4; e++) {
      __hip_fp8_e4m3 c1(fa[g * 4 + e] * i1); // OCP e4m3fn
      __hip_fp8_e4m3 c2(fb[g * 4 + e] * i2);
      v1 |= ((unsigned int)c1.__x) << (8 * e);
      v2 |= ((unsigned int)c2.__x) << (8 * e);
    }
    u1[g] = v1; u2[g] = v2;
  }
  ((unsigned int*)q1)[(size_t)row * 128 + lane] = u1[0];
  ((unsigned int*)q1)[(size_t)row * 128 + 64 + lane] = u1[1];
  ((unsigned int*)q2)[(size_t)row * 128 + lane] = u2[0];
  ((unsigned int*)q2)[(size_t)row * 128 + 64 + lane] = u2[1];
  if (lane == 0) diag[row] = dd * i1 * i2;
}

// ---------------- staging: one 64B k-chunk of A and B into ring buffer --------------
// Per-thread base pointers precomputed (src swizzle folded in); k0 is wave-uniform.
// LDS slot s holds chunk (s ^ ((row>>1)&3)) of its row.
__device__ __forceinline__ void stage_pair(
    const unsigned char* pA, const unsigned char* pB,
    unsigned char (*Ab)[BM * BK], unsigned char (*Bb)[BM * BK],
    int ldst, int chunk) {
  int buf = chunk & 3;
  int k0 = chunk * BK;
  gload_lds16(pA + k0, &Ab[buf][ldst]);
  gload_lds16(pA + 64 * D + k0, &Ab[buf][4096 + ldst]);
  gload_lds16(pB + k0, &Bb[buf][ldst]);
  gload_lds16(pB + 64 * D + k0, &Bb[buf][4096 + ldst]);
}

// ---------------- 128x128 MX fp8 tile: counted-vmcnt pipelined k-loop ----------------
// 8 rounds of BK=64 over a 4-slot ring, 3 chunks in flight. Raw s_barrier + counted
// s_waitcnt vmcnt(8) keeps 2 future chunks' loads in flight ACROSS the barrier (T3/T4):
// the per-round drain-to-0 of __syncthreads was the R1/R2 stall. Reuse safety: stage
// of chunk p+3 (issued after barrier p) overwrites chunk p-1's slot, whose ds_reads
// completed (lgkm-drained) before round p-1's MFMAs, hence before barrier p.
#define SG_ROUND(p, VM)                                                        \
  {                                                                            \
    asm volatile("s_waitcnt vmcnt(" #VM ")" ::: "memory");                     \
    __builtin_amdgcn_s_barrier();                                              \
    __builtin_amdgcn_sched_barrier(0);                                         \
    if ((p) < 5) stage_pair(pA, pB, Ab, Bb, ldst, (p) + 3);                    \
    const unsigned char* Ac = Ab[(p) & 3];                                     \
    const unsigned char* Bc = Bb[(p) & 3];                                     \
    i32x8 af[2], bf[2];                                                        \
    _Pragma("unroll")                                                          \
    for (int i = 0; i < 2; i++) {                                              \
      i32x4 lo = *(const i32x4*)(Ac + offA[i][0]);                             \
      i32x4 hi = *(const i32x4*)(Ac + offA[i][1]);                             \
      af[i] = __builtin_shufflevector(lo, hi, 0, 1, 2, 3, 4, 5, 6, 7);         \
      lo = *(const i32x4*)(Bc + offB[i][0]);                                   \
      hi = *(const i32x4*)(Bc + offB[i][1]);                                   \
      bf[i] = __builtin_shufflevector(lo, hi, 0, 1, 2, 3, 4, 5, 6, 7);         \
    }                                                                          \
    asm volatile("s_waitcnt lgkmcnt(0)" ::: "memory");                         \
    __builtin_amdgcn_sched_barrier(0);                                         \
    __builtin_amdgcn_s_setprio(1);                                             \
    _Pragma("unroll")                                                          \
    for (int i = 0; i < 2; i++)                                                \
      _Pragma("unroll")                                                        \
      for (int j = 0; j < 2; j++)                                              \
        acc[i][j] = __builtin_amdgcn_mfma_scale_f32_32x32x64_f8f6f4(           \
            af[i], bf[j], acc[i][j], 0, 0, 0, 0x7F7F7F7F, 0, 0x7F7F7F7F);      \
    __builtin_amdgcn_s_setprio(0);                                             \
    __builtin_amdgcn_sched_barrier(0);                                         \
  }

__device__ __forceinline__ void mm_tile_mx(
    const unsigned char* __restrict__ X, const unsigned char* __restrict__ Y,
    int r0, int c0, unsigned char (*Ab)[BM * BK], unsigned char (*Bb)[BM * BK],
    f32x16 (&acc)[2][2], int t, int l31, int h, int rw, int cw) {
#pragma unroll
  for (int i = 0; i < 2; i++)
#pragma unroll
    for (int j = 0; j < 2; j++)
#pragma unroll
      for (int r = 0; r < 16; r++) acc[i][j][r] = 0.0f;

  // staging pointers: slot s = t -> row = t>>2, src chunk = (t&3)^((t>>3)&3)
  int srow = t >> 2;
  int ssrc = (t & 3) ^ ((t >> 3) & 3);
  const unsigned char* pA = X + (size_t)(r0 + srow) * D + ssrc * 16;
  const unsigned char* pB = Y + (size_t)(c0 + srow) * D + ssrc * 16;
  int ldst = t * 16;

  // kc-invariant fragment LDS offsets (within an 8KB buffer):
  // lane (l31,h) reads chunks {2h,2h+1} of its row, through the staging swizzle.
  int offA[2][2], offB[2][2];
#pragma unroll
  for (int i = 0; i < 2; i++) {
    int row = rw * 64 + i * 32 + l31;
    int sw = (row >> 1) & 3;
    offA[i][0] = row * 64 + (((h << 1) | 0) ^ sw) * 16;
    offA[i][1] = row * 64 + (((h << 1) | 1) ^ sw) * 16;
  }
#pragma unroll
  for (int j = 0; j < 2; j++) {
    int row = cw * 64 + j * 32 + l31;
    int sw = (row >> 1) & 3;
    offB[j][0] = row * 64 + (((h << 1) | 0) ^ sw) * 16;
    offB[j][1] = row * 64 + (((h << 1) | 1) ^ sw) * 16;
  }

  stage_pair(pA, pB, Ab, Bb, ldst, 0);
  stage_pair(pA, pB, Ab, Bb, ldst, 1);
  stage_pair(pA, pB, Ab, Bb, ldst, 2);

  SG_ROUND(0, 8) SG_ROUND(1, 8) SG_ROUND(2, 8) SG_ROUND(3, 8)
  SG_ROUND(4, 8) SG_ROUND(5, 8) SG_ROUND(6, 4) SG_ROUND(7, 0)
}

// ---------------- fused S + G pass: one 128x128 tile per block ----------------
// 32x32 C/D layout: col = lane&31, row = (reg&3) + 8*(reg>>2) + 4*(lane>>5)
__global__ __launch_bounds__(256, 2) void sg_kernel(
    const unsigned char* __restrict__ q1, const unsigned char* __restrict__ q2,
    float* __restrict__ rowS, float* __restrict__ colS,
    float* __restrict__ partG) {
  __shared__ unsigned char Ab[4][BM * BK]; // 32 KB ring (A)
  __shared__ unsigned char Bb[4][BM * BK]; // 32 KB ring (B)
  // reductions alias the (dead after k-loop) A ring; guarded by a barrier.
  float (*redA)[BM] = reinterpret_cast<float (*)[BM]>(&Ab[0][0]);
  float (*redB)[BM] = reinterpret_cast<float (*)[BM]>(&Ab[0][0] + 1024);

  int bx = blockIdx.x;
  int t = threadIdx.x;
  int lane = t & 63;
  int wave = t >> 6;
  int l31 = lane & 31;
  int h = lane >> 5; // k-half for frags / row-half for C/D
  int rw = wave >> 1;
  int cw = wave & 1;
  const float scale = 1.4426950408889634f / 0.04f; // log2(e)/T

  bool smode = bx < S_BLOCKS;
  const unsigned char* X;
  const unsigned char* Y;
  int r0, c0, ga = 0, gb = 0, gg = 0;
  bool diagb = false;
  if (smode) {
    r0 = (bx >> 6) * BM;
    c0 = (bx & 63) * BM;
    X = q1; Y = q2;
  } else {
    int gx = bx - S_BLOCKS;
    gg = (gx >= TRI) ? 1 : 0;
    int tri = gx - gg * TRI;
    int a = (int)((sqrtf(8.0f * (float)tri + 1.0f) - 1.0f) * 0.5f);
    while ((a + 1) * (a + 2) / 2 <= tri) a++;
    while (a * (a + 1) / 2 > tri) a--;
    int b = tri - a * (a + 1) / 2; // b <= a
    ga = a; gb = b;
    X = gg ? q2 : q1; Y = X;
    r0 = a * BM;
    c0 = b * BM;
    diagb = (a == b);
  }

  f32x16 acc[2][2];
  mm_tile_mx(X, Y, r0, c0, Ab, Bb, acc, t, l31, h, rw, cw);

  __syncthreads(); // all LDS reads done before red* (aliases Ab) is written

  if (smode) {
    // ---- row + col sums of exp2(scale*g); fixed reference (fits fp32) ----
    float csum[2] = {0.0f, 0.0f};
#pragma unroll
    for (int i = 0; i < 2; i++) {
      float rsum[16];
#pragma unroll
      for (int reg = 0; reg < 16; reg++) rsum[reg] = 0.0f;
#pragma unroll
      for (int j = 0; j < 2; j++)
#pragma unroll
        for (int reg = 0; reg < 16; reg++) {
          float e = __builtin_amdgcn_exp2f(acc[i][j][reg] * scale);
          rsum[reg] += e;
          csum[j] += e;
        }
      // row-sum: reduce across the 32 lanes of this k/row-half (bit5 preserved)
#pragma unroll
      for (int reg = 0; reg < 16; reg++) {
#pragma unroll
        for (int off = 1; off < 32; off <<= 1) rsum[reg] += __shfl_xor(rsum[reg], off);
      }
      if (l31 == 0) {
#pragma unroll
        for (int reg = 0; reg < 16; reg++) {
          int rloc = (reg & 3) + 8 * (reg >> 2) + 4 * h;
          redB[cw][rw * 64 + i * 32 + rloc] = rsum[reg];
        }
      }
    }
    // col-sum: add the other row-half, then one lane-half writes
#pragma unroll
    for (int j = 0; j < 2; j++) {
      csum[j] += __shfl_xor(csum[j], 32);
      if (h == 0) redA[rw][cw * 64 + j * 32 + l31] = csum[j];
    }
    __syncthreads();
    if (t < BM) {
      colS[(size_t)(r0 >> 7) * N + c0 + t] = redA[0][t] + redA[1][t];
      rowS[(size_t)(c0 >> 7) * N + r0 + t] = redB[0][t] + redB[1][t];
    }
  } else {
    // ---- Gram: row max (strip a), diag-masked; col max = row max of strip b ----
#pragma unroll
    for (int i = 0; i < 2; i++) {
      float rmax[16];
#pragma unroll
      for (int reg = 0; reg < 16; reg++) {
        int rloc = (reg & 3) + 8 * (reg >> 2) + 4 * h;
        int rr = rw * 64 + i * 32 + rloc;
        float v = -3.0e38f;
#pragma unroll
        for (int j = 0; j < 2; j++) {
          float x = acc[i][j][reg];
          int cc = cw * 64 + j * 32 + l31;
          if (diagb && cc == rr) x = -3.0e38f;
          v = fmaxf(v, x);
        }
        rmax[reg] = v;
      }
#pragma unroll
      for (int reg = 0; reg < 16; reg++) {
#pragma unroll
        for (int off = 1; off < 32; off <<= 1) rmax[reg] = fmaxf(rmax[reg], __shfl_xor(rmax[reg], off));
      }
      if (l31 == 0) {
#pragma unroll
        for (int reg = 0; reg < 16; reg++) {
          int rloc = (reg & 3) + 8 * (reg >> 2) + 4 * h;
          redA[cw][rw * 64 + i * 32 + rloc] = rmax[reg];
        }
      }
    }
    if (!diagb) {
#pragma unroll
      for (int j = 0; j < 2; j++) {
        float m = -3.0e38f;
#pragma unroll
        for (int i = 0; i < 2; i++)
#pragma unroll
          for (int reg = 0; reg < 16; reg++) m = fmaxf(m, acc[i][j][reg]);
        m = fmaxf(m, __shfl_xor(m, 32));
        if (h == 0) redB[rw][cw * 64 + j * 32 + l31] = m;
      }
    }
    __syncthreads();
    if (t < BM) {
      partG[((size_t)(gg * NSTRIP + gb)) * N + r0 + t] = fmaxf(redA[0][t], redA[1][t]);
      if (!diagb)
        partG[((size_t)(gg * NSTRIP + ga)) * N + c0 + t] = fmaxf(redB[0][t], redB[1][t]);
    }
  }
}

// ---------------- per-row combine of partials -> atomic scalar ----------------
__global__ __launch_bounds__(256) void combine_kernel(
    const float* __restrict__ diag,
    const float* __restrict__ rowS, const float* __restrict__ colS,
    const float* __restrict__ partG, float* __restrict__ out) {
  int t = threadIdx.x;
  int l = t & 63;
  int w = t >> 6;
  int i = blockIdx.x * 64 + l;

  float sR = 0.0f, sC = 0.0f, g1 = -3.0e38f, g2 = -3.0e38f;
#pragma unroll
  for (int s = 0; s < 16; s++) {
    int strip = w * 16 + s;
    sR += rowS[(size_t)strip * N + i];
    sC += colS[(size_t)strip * N + i];
    g1 = fmaxf(g1, partG[(size_t)strip * N + i]);
    g2 = fmaxf(g2, partG[(size_t)(NSTRIP + strip) * N + i]);
  }
  __shared__ float red[4][4][64];
  red[0][w][l] = sR; red[1][w][l] = sC; red[2][w][l] = g1; red[3][w][l] = g2;
  __syncthreads();
  if (w == 0) {
    sR = red[0][0][l] + red[0][1][l] + red[0][2][l] + red[0][3][l];
    sC = red[1][0][l] + red[1][1][l] + red[1][2][l] + red[1][3][l];
    g1 = fmaxf(fmaxf(red[2][0][l], red[2][1][l]), fmaxf(red[2][2][l], red[2][3][l]));
    g2 = fmaxf(fmaxf(red[3][0][l], red[3][1][l]), fmaxf(red[3][2][l], red[3][3][l]));
    float dv = diag[i] * 25.0f;
    float a12 = logf(sR) - dv;
    float a21 = logf(sC) - dv;
    float k1 = logf(sqrtf(fmaxf(2.0f - 2.0f * g1, 0.0f)) + 1e-9f);
    float k2 = logf(sqrtf(fmaxf(2.0f - 2.0f * g2, 0.0f)) + 1e-9f);
    float c = 0.5f * (a12 + a21) / (float)N - 0.1f * 0.5f * (k1 + k2) / (float)N;
#pragma unroll
    for (int off = 1; off < 64; off <<= 1) c += __shfl_xor(c, off);
    if (l == 0) atomicAdd(out, c); // device-scope, out zeroed by norm_kernel
  }
}

extern "C" void kernel_launch(void* const* d_in, const int* in_sizes, int n_in,
                              void* d_out, int out_size, void* d_ws, size_t ws_size,
                              hipStream_t stream) {
  const float* z1 = (const float*)d_in[0];
  const float* z2 = (const float*)d_in[1];
  char* w = (char*)d_ws;
  unsigned char* q1 = (unsigned char*)w; w += (size_t)N * D;
  unsigned char* q2 = (unsigned char*)w; w += (size_t)N * D;
  float* diag = (float*)w;   w += (size_t)N * sizeof(float);
  float* rowS = (float*)w;   w += (size_t)NSTRIP * N * sizeof(float);
  float* colS = (float*)w;   w += (size_t)NSTRIP * N * sizeof(float);
  float* partG = (float*)w;  w += (size_t)2 * NSTRIP * N * sizeof(float);
  float* out = (float*)d_out;

  norm_kernel<<<N / 4, 256, 0, stream>>>(z1, z2, q1, q2, diag, out);
  sg_kernel<<<SG_BLOCKS, 256, 0, stream>>>(q1, q2, rowS, colS, partG);
  combine_kernel<<<N / 64, 256, 0, stream>>>(diag, rowS, colS, partG, out);
}

// Round 4
// 222.902 us; speedup vs baseline: 1.0701x; 1.0478x over previous
//
#include <hip/hip_runtime.h>
#include <hip/hip_bf16.h>
#include <hip/hip_fp8.h>
#include <math.h>

#define N 8192
#define D 512
#define BM 256
#define BK 64
#define NSTRIP 32                       // N / BM
#define S_BLOCKS (NSTRIP * NSTRIP)      // 1024 S tiles (32x32 grid)
#define G_BLOCKS 1056                   // 2 grams x TRI(32)=528
#define SG_BLOCKS (S_BLOCKS + G_BLOCKS) // 2080 = 8 XCDs x 260
#define QPX 260

typedef float f32x16 __attribute__((ext_vector_type(16)));
typedef int i32x4 __attribute__((ext_vector_type(4)));
typedef int i32x8 __attribute__((ext_vector_type(8)));

__device__ inline void gload_lds16(const void* g, void* l) {
  __builtin_amdgcn_global_load_lds(
      (const __attribute__((address_space(1))) void*)g,
      (__attribute__((address_space(3))) void*)l, 16, 0, 0);
}

// ---------------- normalize to fp8 e4m3 + exact fp32 diagonal + zero out ----------------
// wave-per-row: 64 lanes x 8 floats = 512 = D; shuffle-only reduction, no barriers.
__global__ __launch_bounds__(256) void norm_kernel(
    const float* __restrict__ z1, const float* __restrict__ z2,
    unsigned char* __restrict__ q1, unsigned char* __restrict__ q2,
    float* __restrict__ diag, float* __restrict__ out) {
  int t = threadIdx.x;
  int lane = t & 63;
  int w = t >> 6;
  int row = blockIdx.x * 4 + w;
  if (blockIdx.x == 0 && t == 0) out[0] = 0.0f; // atomic target (stream-ordered)
  const float4* a = (const float4*)(z1 + (size_t)row * D);
  const float4* b = (const float4*)(z2 + (size_t)row * D);
  float4 xa0 = a[lane], xa1 = a[lane + 64];
  float4 xb0 = b[lane], xb1 = b[lane + 64];
  float ss1 = xa0.x * xa0.x + xa0.y * xa0.y + xa0.z * xa0.z + xa0.w * xa0.w +
              xa1.x * xa1.x + xa1.y * xa1.y + xa1.z * xa1.z + xa1.w * xa1.w;
  float ss2 = xb0.x * xb0.x + xb0.y * xb0.y + xb0.z * xb0.z + xb0.w * xb0.w +
              xb1.x * xb1.x + xb1.y * xb1.y + xb1.z * xb1.z + xb1.w * xb1.w;
  float dd = xa0.x * xb0.x + xa0.y * xb0.y + xa0.z * xb0.z + xa0.w * xb0.w +
             xa1.x * xb1.x + xa1.y * xb1.y + xa1.z * xb1.z + xa1.w * xb1.w;
#pragma unroll
  for (int off = 1; off < 64; off <<= 1) {
    ss1 += __shfl_xor(ss1, off);
    ss2 += __shfl_xor(ss2, off);
    dd  += __shfl_xor(dd,  off);
  }
  float i1 = 1.0f / fmaxf(sqrtf(ss1), 1e-12f);
  float i2 = 1.0f / fmaxf(sqrtf(ss2), 1e-12f);
  float fa[8] = {xa0.x, xa0.y, xa0.z, xa0.w, xa1.x, xa1.y, xa1.z, xa1.w};
  float fb[8] = {xb0.x, xb0.y, xb0.z, xb0.w, xb1.x, xb1.y, xb1.z, xb1.w};
  unsigned int u1[2], u2[2];
#pragma unroll
  for (int g = 0; g < 2; g++) {
    unsigned int v1 = 0, v2 = 0;
#pragma unroll
    for (int e = 0; e < 4; e++) {
      __hip_fp8_e4m3 c1(fa[g * 4 + e] * i1); // OCP e4m3fn
      __hip_fp8_e4m3 c2(fb[g * 4 + e] * i2);
      v1 |= ((unsigned int)c1.__x) << (8 * e);
      v2 |= ((unsigned int)c2.__x) << (8 * e);
    }
    u1[g] = v1; u2[g] = v2;
  }
  ((unsigned int*)q1)[(size_t)row * 128 + lane] = u1[0];
  ((unsigned int*)q1)[(size_t)row * 128 + 64 + lane] = u1[1];
  ((unsigned int*)q2)[(size_t)row * 128 + lane] = u2[0];
  ((unsigned int*)q2)[(size_t)row * 128 + 64 + lane] = u2[1];
  if (lane == 0) diag[row] = dd * i1 * i2;
}

// ---------------- stage one BK=64 chunk of 256-row A and B panels ----------------
// 512 threads x 4 x 16B = 32KB. LDS slot (row, cs) holds global piece cs^((row>>1)&3)
// (conflict-spread swizzle, folded into the per-thread global base pointer).
__device__ __forceinline__ void stage_chunk(
    const unsigned char* pA, const unsigned char* pB,
    unsigned char* ldsb, int t, int chunk) {
  unsigned char* buf = ldsb + (chunk & 3) * 32768;
  int k0 = chunk * BK;
  gload_lds16(pA + k0,           buf + t * 16);          // A rows 0..127
  gload_lds16(pA + 128 * D + k0, buf + 8192 + t * 16);   // A rows 128..255
  gload_lds16(pB + k0,           buf + 16384 + t * 16);  // B rows 0..127
  gload_lds16(pB + 128 * D + k0, buf + 24576 + t * 16);  // B rows 128..255
}

// ---------------- one pipelined round: counted vmcnt, never drain in-loop ----------------
// At round p: chunks p,p+1,p+2 in flight (12 loads/thread). vmcnt(8) lands chunk p's
// 4 loads; barrier makes that true for all waves. Stage p+3 overwrites buf (p-1)&3,
// whose ds_reads were lgkm-drained before round p-1's MFMAs (hence before barrier p).
#define SG_ROUND(p, VM)                                                        \
  {                                                                            \
    asm volatile("s_waitcnt vmcnt(" #VM ")" ::: "memory");                     \
    __builtin_amdgcn_s_barrier();                                              \
    __builtin_amdgcn_sched_barrier(0);                                         \
    if ((p) < 5) stage_chunk(pA, pB, lds, t, (p) + 3);                         \
    const unsigned char* buf = lds + (((p) & 3) * 32768);                      \
    i32x8 af[4], bf[2];                                                        \
    _Pragma("unroll")                                                          \
    for (int i = 0; i < 4; i++) {                                              \
      i32x4 lo = *(const i32x4*)(buf + offA[i][0]);                            \
      i32x4 hi = *(const i32x4*)(buf + offA[i][1]);                            \
      af[i] = __builtin_shufflevector(lo, hi, 0, 1, 2, 3, 4, 5, 6, 7);         \
    }                                                                          \
    _Pragma("unroll")                                                          \
    for (int j = 0; j < 2; j++) {                                              \
      i32x4 lo = *(const i32x4*)(buf + 16384 + offB[j][0]);                    \
      i32x4 hi = *(const i32x4*)(buf + 16384 + offB[j][1]);                    \
      bf[j] = __builtin_shufflevector(lo, hi, 0, 1, 2, 3, 4, 5, 6, 7);         \
    }                                                                          \
    asm volatile("s_waitcnt lgkmcnt(0)" ::: "memory");                         \
    __builtin_amdgcn_sched_barrier(0);                                         \
    __builtin_amdgcn_s_setprio(1);                                             \
    _Pragma("unroll")                                                          \
    for (int i = 0; i < 4; i++)                                                \
      _Pragma("unroll")                                                        \
      for (int j = 0; j < 2; j++)                                              \
        acc[i][j] = __builtin_amdgcn_mfma_scale_f32_32x32x64_f8f6f4(           \
            af[i], bf[j], acc[i][j], 0, 0, 0, 0x7F7F7F7F, 0, 0x7F7F7F7F);      \
    __builtin_amdgcn_s_setprio(0);                                             \
    __builtin_amdgcn_sched_barrier(0);                                         \
  }

// ---------------- fused S + G pass: one 256x256 tile per block, 8 waves ----------------
// Wave (rw=wv>>2, cw=wv&3) owns rows [rw*128,+128) x cols [cw*64,+64): acc[4][2] of
// 32x32. C/D layout: col = lane&31, row = (reg&3) + 8*(reg>>2) + 4*(lane>>5).
// Block->tile map is XCD-aware (xcd = bx&7 round-robin heuristic): each XCD gets an
// 8x16 S sub-grid (A 1MB + B 2MB < 4MB L2) and self-contained 4-strip G group-pairs
// (1MB each) so staging is served by the local L2, not L3.
__global__ __launch_bounds__(512, 2) void sg_kernel(
    const unsigned char* __restrict__ q1, const unsigned char* __restrict__ q2,
    float* __restrict__ rowS, float* __restrict__ colS,
    float* __restrict__ partG) {
  extern __shared__ unsigned char lds[]; // 128KB: 4-slot ring x (16KB A + 16KB B)
  float (*redR)[256] = (float (*)[256])lds;          // [4][256], aliases buf0 (dead)
  float (*redC)[256] = (float (*)[256])(lds + 4096); // [2][256]

  int bx = blockIdx.x;
  int x = bx & 7;   // XCD (round-robin dispatch heuristic; perf-only)
  int q = bx >> 3;  // 0..259 per-XCD sequence
  int t = threadIdx.x;
  int lane = t & 63;
  int wv = t >> 6;
  int l31 = lane & 31;
  int h = lane >> 5;
  int rw = wv >> 2; // 0..1
  int cw = wv & 3;  // 0..3
  const float scale = 1.4426950408889634f / 0.04f; // log2(e)/T

  bool smode = q < 128;
  const unsigned char* X;
  const unsigned char* Y;
  int r0, c0, ga = 0, gb = 0, gg = 0;
  bool diagb = false;
  if (smode) {
    int u = x >> 1, v = x & 1;
    int r = u * 8 + (q >> 4);   // 8 strip-rows per XCD
    int c = v * 16 + (q & 15);  // 16 strip-cols per XCD
    r0 = r * BM; c0 = c * BM;
    X = q1; Y = q2;
  } else {
    int qq = q - 128; // 0..131
    int a4, b4, g;
    if (qq < 20) {
      // two diagonal group-pairs: (g, group i = x), TRI(4)=10 tiles each
      g = qq / 10;
      int tt = qq - g * 10;
      int da = (int)((sqrtf(8.0f * (float)tt + 1.0f) - 1.0f) * 0.5f);
      while ((da + 1) * (da + 2) / 2 <= tt) da++;
      while (da * (da + 1) / 2 > tt) da--;
      int db = tt - da * (da + 1) / 2;
      a4 = x * 4 + da; b4 = x * 4 + db;
    } else {
      // 7 off-diagonal group-pairs x 16 tiles; pidx = x + 8n over 56 pairs
      int e = qq - 20;
      int n = e >> 4;
      int tt = e & 15;
      int pidx = x + 8 * n;
      g = (pidx >= 28) ? 1 : 0;
      int p = pidx - g * 28; // 0..27 = i(i-1)/2 + j, i>j, i in 1..7
      int i = (int)((sqrtf(8.0f * (float)p + 1.0f) + 1.0f) * 0.5f);
      while (i * (i - 1) / 2 > p) i--;
      while ((i + 1) * i / 2 <= p) i++;
      int j = p - i * (i - 1) / 2;
      a4 = i * 4 + (tt >> 2); b4 = j * 4 + (tt & 3);
    }
    ga = a4; gb = b4; gg = g;
    X = g ? q2 : q1; Y = X;
    r0 = a4 * BM; c0 = b4 * BM;
    diagb = (a4 == b4);
  }

  // kc-invariant fragment LDS offsets; lane (l31,h) reads pieces {2h,2h+1} of its row.
  int offA[4][2], offB[2][2];
#pragma unroll
  for (int i = 0; i < 4; i++) {
    int row = rw * 128 + i * 32 + l31;
    int sw = (row >> 1) & 3;
    offA[i][0] = row * 64 + (((h << 1) | 0) ^ sw) * 16;
    offA[i][1] = row * 64 + (((h << 1) | 1) ^ sw) * 16;
  }
#pragma unroll
  for (int j = 0; j < 2; j++) {
    int row = cw * 64 + j * 32 + l31;
    int sw = (row >> 1) & 3;
    offB[j][0] = row * 64 + (((h << 1) | 0) ^ sw) * 16;
    offB[j][1] = row * 64 + (((h << 1) | 1) ^ sw) * 16;
  }

  // staging base pointers (src swizzle folded; row+128 has identical swizzle)
  int srow = t >> 2;
  int ssrc = (t & 3) ^ ((t >> 3) & 3);
  const unsigned char* pA = X + (size_t)(r0 + srow) * D + ssrc * 16;
  const unsigned char* pB = Y + (size_t)(c0 + srow) * D + ssrc * 16;

  f32x16 acc[4][2];
#pragma unroll
  for (int i = 0; i < 4; i++)
#pragma unroll
    for (int j = 0; j < 2; j++)
#pragma unroll
      for (int r = 0; r < 16; r++) acc[i][j][r] = 0.0f;

  stage_chunk(pA, pB, lds, t, 0);
  stage_chunk(pA, pB, lds, t, 1);
  stage_chunk(pA, pB, lds, t, 2);

  SG_ROUND(0, 8) SG_ROUND(1, 8) SG_ROUND(2, 8) SG_ROUND(3, 8)
  SG_ROUND(4, 8) SG_ROUND(5, 8) SG_ROUND(6, 4) SG_ROUND(7, 0)

  __syncthreads(); // ring dead; reuse as reduction scratch

  if (smode) {
    // ---- row + col sums of exp2(scale*g) ----
    float csum[2] = {0.0f, 0.0f};
#pragma unroll
    for (int i = 0; i < 4; i++) {
      float rsum[16];
#pragma unroll
      for (int r = 0; r < 16; r++) rsum[r] = 0.0f;
#pragma unroll
      for (int j = 0; j < 2; j++)
#pragma unroll
        for (int r = 0; r < 16; r++) {
          float e = __builtin_amdgcn_exp2f(acc[i][j][r] * scale);
          rsum[r] += e;
          csum[j] += e;
        }
#pragma unroll
      for (int r = 0; r < 16; r++) {
#pragma unroll
        for (int off = 1; off < 32; off <<= 1) rsum[r] += __shfl_xor(rsum[r], off);
      }
      if (l31 == 0) {
#pragma unroll
        for (int r = 0; r < 16; r++) {
          int rloc = (r & 3) + 8 * (r >> 2) + 4 * h;
          redR[cw][rw * 128 + i * 32 + rloc] = rsum[r];
        }
      }
    }
#pragma unroll
    for (int j = 0; j < 2; j++) {
      csum[j] += __shfl_xor(csum[j], 32);
      if (h == 0) redC[rw][cw * 64 + j * 32 + l31] = csum[j];
    }
    __syncthreads();
    if (t < BM) {
      rowS[(size_t)(c0 >> 8) * N + r0 + t] =
          redR[0][t] + redR[1][t] + redR[2][t] + redR[3][t];
      colS[(size_t)(r0 >> 8) * N + c0 + t] = redC[0][t] + redC[1][t];
    }
  } else {
    // ---- Gram: row max (strip a), diag-masked; col max (strip b) ----
#pragma unroll
    for (int i = 0; i < 4; i++) {
      float rmax[16];
#pragma unroll
      for (int r = 0; r < 16; r++) {
        int rloc = (r & 3) + 8 * (r >> 2) + 4 * h;
        int rr = rw * 128 + i * 32 + rloc;
        float v = -3.0e38f;
#pragma unroll
        for (int j = 0; j < 2; j++) {
          float xv = acc[i][j][r];
          int cc = cw * 64 + j * 32 + l31;
          if (diagb && cc == rr) xv = -3.0e38f;
          v = fmaxf(v, xv);
        }
        rmax[r] = v;
      }
#pragma unroll
      for (int r = 0; r < 16; r++) {
#pragma unroll
        for (int off = 1; off < 32; off <<= 1) rmax[r] = fmaxf(rmax[r], __shfl_xor(rmax[r], off));
      }
      if (l31 == 0) {
#pragma unroll
        for (int r = 0; r < 16; r++) {
          int rloc = (r & 3) + 8 * (r >> 2) + 4 * h;
          redR[cw][rw * 128 + i * 32 + rloc] = rmax[r];
        }
      }
    }
    if (!diagb) {
#pragma unroll
      for (int j = 0; j < 2; j++) {
        float m = -3.0e38f;
#pragma unroll
        for (int i = 0; i < 4; i++)
#pragma unroll
          for (int r = 0; r < 16; r++) m = fmaxf(m, acc[i][j][r]);
        m = fmaxf(m, __shfl_xor(m, 32));
        if (h == 0) redC[rw][cw * 64 + j * 32 + l31] = m;
      }
    }
    __syncthreads();
    if (t < BM) {
      partG[((size_t)(gg * NSTRIP + gb)) * N + r0 + t] =
          fmaxf(fmaxf(redR[0][t], redR[1][t]), fmaxf(redR[2][t], redR[3][t]));
      if (!diagb)
        partG[((size_t)(gg * NSTRIP + ga)) * N + c0 + t] = fmaxf(redC[0][t], redC[1][t]);
    }
  }
}

// ---------------- per-row combine of partials -> atomic scalar ----------------
__global__ __launch_bounds__(256) void combine_kernel(
    const float* __restrict__ diag,
    const float* __restrict__ rowS, const float* __restrict__ colS,
    const float* __restrict__ partG, float* __restrict__ out) {
  int t = threadIdx.x;
  int l = t & 63;
  int w = t >> 6;
  int i = blockIdx.x * 64 + l;

  float sR = 0.0f, sC = 0.0f, g1 = -3.0e38f, g2 = -3.0e38f;
#pragma unroll
  for (int s = 0; s < 8; s++) {
    int strip = w * 8 + s;
    sR += rowS[(size_t)strip * N + i];
    sC += colS[(size_t)strip * N + i];
    g1 = fmaxf(g1, partG[(size_t)strip * N + i]);
    g2 = fmaxf(g2, partG[(size_t)(NSTRIP + strip) * N + i]);
  }
  __shared__ float red[4][4][64];
  red[0][w][l] = sR; red[1][w][l] = sC; red[2][w][l] = g1; red[3][w][l] = g2;
  __syncthreads();
  if (w == 0) {
    sR = red[0][0][l] + red[0][1][l] + red[0][2][l] + red[0][3][l];
    sC = red[1][0][l] + red[1][1][l] + red[1][2][l] + red[1][3][l];
    g1 = fmaxf(fmaxf(red[2][0][l], red[2][1][l]), fmaxf(red[2][2][l], red[2][3][l]));
    g2 = fmaxf(fmaxf(red[3][0][l], red[3][1][l]), fmaxf(red[3][2][l], red[3][3][l]));
    float dv = diag[i] * 25.0f;
    float a12 = logf(sR) - dv;
    float a21 = logf(sC) - dv;
    float k1 = logf(sqrtf(fmaxf(2.0f - 2.0f * g1, 0.0f)) + 1e-9f);
    float k2 = logf(sqrtf(fmaxf(2.0f - 2.0f * g2, 0.0f)) + 1e-9f);
    float c = 0.5f * (a12 + a21) / (float)N - 0.1f * 0.5f * (k1 + k2) / (float)N;
#pragma unroll
    for (int off = 1; off < 64; off <<= 1) c += __shfl_xor(c, off);
    if (l == 0) atomicAdd(out, c); // device-scope, out zeroed by norm_kernel
  }
}

extern "C" void kernel_launch(void* const* d_in, const int* in_sizes, int n_in,
                              void* d_out, int out_size, void* d_ws, size_t ws_size,
                              hipStream_t stream) {
  const float* z1 = (const float*)d_in[0];
  const float* z2 = (const float*)d_in[1];
  char* w = (char*)d_ws;
  unsigned char* q1 = (unsigned char*)w; w += (size_t)N * D;
  unsigned char* q2 = (unsigned char*)w; w += (size_t)N * D;
  float* diag = (float*)w;   w += (size_t)N * sizeof(float);
  float* rowS = (float*)w;   w += (size_t)NSTRIP * N * sizeof(float);
  float* colS = (float*)w;   w += (size_t)NSTRIP * N * sizeof(float);
  float* partG = (float*)w;  w += (size_t)2 * NSTRIP * N * sizeof(float);
  float* out = (float*)d_out;

  static bool attr_done = false;
  if (!attr_done) {
    hipFuncSetAttribute((const void*)sg_kernel,
                        hipFuncAttributeMaxDynamicSharedMemorySize, 131072);
    attr_done = true;
  }

  norm_kernel<<<N / 4, 256, 0, stream>>>(z1, z2, q1, q2, diag, out);
  sg_kernel<<<SG_BLOCKS, 512, 131072, stream>>>(q1, q2, rowS, colS, partG);
  combine_kernel<<<N / 64, 256, 0, stream>>>(diag, rowS, colS, partG, out);
}

// Round 5
// 199.882 us; speedup vs baseline: 1.1933x; 1.1152x over previous
//
#include <hip/hip_runtime.h>
#include <hip/hip_bf16.h>
#include <hip/hip_fp8.h>
#include <math.h>

#define N 8192
#define D 512
#define BM 128
#define BK 64
#define NSTRIP 64                       // N / BM
#define S_BLOCKS (NSTRIP * NSTRIP)      // 4096 S tiles
#define TRI (NSTRIP * (NSTRIP + 1) / 2) // 2080
#define G_BLOCKS (2 * TRI)              // 4160 Gram tiles
#define SG_BLOCKS (S_BLOCKS + G_BLOCKS) // 8256

typedef float f32x16 __attribute__((ext_vector_type(16)));
typedef int i32x4 __attribute__((ext_vector_type(4)));
typedef int i32x8 __attribute__((ext_vector_type(8)));

__device__ inline void gload_lds16(const void* g, void* l) {
  __builtin_amdgcn_global_load_lds(
      (const __attribute__((address_space(1))) void*)g,
      (__attribute__((address_space(3))) void*)l, 16, 0, 0);
}

// ---------------- normalize to fp8 e4m3 + exact fp32 diagonal + zero out ----------------
// wave-per-row: 64 lanes x 8 floats = 512 = D; shuffle-only reduction, no barriers.
__global__ __launch_bounds__(256) void norm_kernel(
    const float* __restrict__ z1, const float* __restrict__ z2,
    unsigned char* __restrict__ q1, unsigned char* __restrict__ q2,
    float* __restrict__ diag, float* __restrict__ out) {
  int t = threadIdx.x;
  int lane = t & 63;
  int w = t >> 6;
  int row = blockIdx.x * 4 + w;
  if (blockIdx.x == 0 && t == 0) out[0] = 0.0f; // atomic target (stream-ordered)
  const float4* a = (const float4*)(z1 + (size_t)row * D);
  const float4* b = (const float4*)(z2 + (size_t)row * D);
  float4 xa0 = a[lane], xa1 = a[lane + 64];
  float4 xb0 = b[lane], xb1 = b[lane + 64];
  float ss1 = xa0.x * xa0.x + xa0.y * xa0.y + xa0.z * xa0.z + xa0.w * xa0.w +
              xa1.x * xa1.x + xa1.y * xa1.y + xa1.z * xa1.z + xa1.w * xa1.w;
  float ss2 = xb0.x * xb0.x + xb0.y * xb0.y + xb0.z * xb0.z + xb0.w * xb0.w +
              xb1.x * xb1.x + xb1.y * xb1.y + xb1.z * xb1.z + xb1.w * xb1.w;
  float dd = xa0.x * xb0.x + xa0.y * xb0.y + xa0.z * xb0.z + xa0.w * xb0.w +
             xa1.x * xb1.x + xa1.y * xb1.y + xa1.z * xb1.z + xa1.w * xb1.w;
#pragma unroll
  for (int off = 1; off < 64; off <<= 1) {
    ss1 += __shfl_xor(ss1, off);
    ss2 += __shfl_xor(ss2, off);
    dd  += __shfl_xor(dd,  off);
  }
  float i1 = 1.0f / fmaxf(sqrtf(ss1), 1e-12f);
  float i2 = 1.0f / fmaxf(sqrtf(ss2), 1e-12f);
  float fa[8] = {xa0.x, xa0.y, xa0.z, xa0.w, xa1.x, xa1.y, xa1.z, xa1.w};
  float fb[8] = {xb0.x, xb0.y, xb0.z, xb0.w, xb1.x, xb1.y, xb1.z, xb1.w};
  unsigned int u1[2], u2[2];
#pragma unroll
  for (int g = 0; g < 2; g++) {
    unsigned int v1 = 0, v2 = 0;
#pragma unroll
    for (int e = 0; e < 4; e++) {
      __hip_fp8_e4m3 c1(fa[g * 4 + e] * i1); // OCP e4m3fn
      __hip_fp8_e4m3 c2(fb[g * 4 + e] * i2);
      v1 |= ((unsigned int)c1.__x) << (8 * e);
      v2 |= ((unsigned int)c2.__x) << (8 * e);
    }
    u1[g] = v1; u2[g] = v2;
  }
  ((unsigned int*)q1)[(size_t)row * 128 + lane] = u1[0];
  ((unsigned int*)q1)[(size_t)row * 128 + 64 + lane] = u1[1];
  ((unsigned int*)q2)[(size_t)row * 128 + lane] = u2[0];
  ((unsigned int*)q2)[(size_t)row * 128 + 64 + lane] = u2[1];
  if (lane == 0) diag[row] = dd * i1 * i2;
}

// ---------------- stage one BK=64 chunk (A 8KB + B 8KB) into dbuf slot chunk&1 --------
// Conflict-free swizzle: LDS slot (row, cs) holds global piece cs ^ u(row) ^ f(row),
// u=(row>>4)&1, f=(row>>1)&3 (folded into per-thread base pointer: uniform in it).
__device__ __forceinline__ void stage_chunk(
    const unsigned char* pA, const unsigned char* pB,
    unsigned char (*lds)[16384], int t, int chunk) {
  unsigned char* buf = lds[chunk & 1];
  int k0 = chunk * BK;
  gload_lds16(pA + k0,          buf + t * 16);           // A rows 0..63
  gload_lds16(pA + 64 * D + k0, buf + 4096 + t * 16);    // A rows 64..127
  gload_lds16(pB + k0,          buf + 8192 + t * 16);    // B rows 0..63
  gload_lds16(pB + 64 * D + k0, buf + 12288 + t * 16);   // B rows 64..127
}

// ---------------- one round: drain own stage, barrier, stage next, read, 4 MFMA -------
// dbuf-2 R0-style schedule (the only schedule that ever hit per-block throughput);
// throughput comes from 4-5 desynchronized resident blocks, not in-block pipelining.
// Reuse safety: stage(p+1) overwrites buf holding chunk p-1, whose ds_reads were
// lgkm-drained before round p-1's MFMAs, hence before barrier p.
#define SG_ROUND(p)                                                            \
  {                                                                            \
    asm volatile("s_waitcnt vmcnt(0)" ::: "memory");                           \
    __builtin_amdgcn_s_barrier();                                              \
    __builtin_amdgcn_sched_barrier(0);                                         \
    if ((p) < 7) stage_chunk(pA, pB, lds, t, (p) + 1);                         \
    const unsigned char* buf = lds[(p) & 1];                                   \
    i32x8 af[2], bf[2];                                                        \
    _Pragma("unroll")                                                          \
    for (int i = 0; i < 2; i++) {                                              \
      i32x4 lo = *(const i32x4*)(buf + offA[i]);                               \
      i32x4 hi = *(const i32x4*)(buf + (offA[i] ^ 16));                        \
      af[i] = __builtin_shufflevector(lo, hi, 0, 1, 2, 3, 4, 5, 6, 7);         \
      lo = *(const i32x4*)(buf + offB[i]);                                     \
      hi = *(const i32x4*)(buf + (offB[i] ^ 16));                              \
      bf[i] = __builtin_shufflevector(lo, hi, 0, 1, 2, 3, 4, 5, 6, 7);         \
    }                                                                          \
    asm volatile("s_waitcnt lgkmcnt(0)" ::: "memory");                         \
    __builtin_amdgcn_sched_barrier(0);                                         \
    __builtin_amdgcn_s_setprio(1);                                             \
    _Pragma("unroll")                                                          \
    for (int i = 0; i < 2; i++)                                                \
      _Pragma("unroll")                                                        \
      for (int j = 0; j < 2; j++)                                              \
        acc[i][j] = __builtin_amdgcn_mfma_scale_f32_32x32x64_f8f6f4(           \
            af[i], bf[j], acc[i][j], 0, 0, 0, 0x7F7F7F7F, 0, 0x7F7F7F7F);      \
    __builtin_amdgcn_s_setprio(0);                                             \
    __builtin_amdgcn_sched_barrier(0);                                         \
  }

// ---------------- fused S + G pass: one 128x128 tile per block, 4 waves ----------------
// 32x32 C/D layout: col = lane&31, row = (reg&3) + 8*(reg>>2) + 4*(lane>>5).
// Fragment read pattern: each quarter-wave reads 16 consecutive rows with piece
// q ^ f(row) -- the access shape that measured ZERO bank conflicts in R0.
__global__ __launch_bounds__(256, 4) void sg_kernel(
    const unsigned char* __restrict__ q1, const unsigned char* __restrict__ q2,
    float* __restrict__ rowS, float* __restrict__ colS,
    float* __restrict__ partG) {
  __shared__ unsigned char lds[2][16384]; // 32 KB dbuf: [A 8KB | B 8KB] per slot
  // reductions alias buf0 (dead after k-loop; guarded by barrier)
  float (*redA)[BM] = reinterpret_cast<float (*)[BM]>(&lds[0][0]);
  float (*redB)[BM] = reinterpret_cast<float (*)[BM]>(&lds[0][0] + 1024);

  int bx = blockIdx.x;
  int t = threadIdx.x;
  int lane = t & 63;
  int wave = t >> 6;
  int l31 = lane & 31;
  int h = lane >> 5; // k-half for frags / row-half for C/D
  int rw = wave >> 1;
  int cw = wave & 1;
  const float scale = 1.4426950408889634f / 0.04f; // log2(e)/T

  bool smode = bx < S_BLOCKS;
  const unsigned char* X;
  const unsigned char* Y;
  int r0, c0, ga = 0, gb = 0, gg = 0;
  bool diagb = false;
  if (smode) {
    r0 = (bx >> 6) * BM;
    c0 = (bx & 63) * BM;
    X = q1; Y = q2;
  } else {
    int gx = bx - S_BLOCKS;
    gg = (gx >= TRI) ? 1 : 0;
    int tri = gx - gg * TRI;
    int a = (int)((sqrtf(8.0f * (float)tri + 1.0f) - 1.0f) * 0.5f);
    while ((a + 1) * (a + 2) / 2 <= tri) a++;
    while (a * (a + 1) / 2 > tri) a--;
    int b = tri - a * (a + 1) / 2; // b <= a
    ga = a; gb = b;
    X = gg ? q2 : q1; Y = X;
    r0 = a * BM;
    c0 = b * BM;
    diagb = (a == b);
  }

  // fragment LDS byte offsets (conflict-free swizzle). u,f depend only on l31.
  // piece(b) = 2h ^ b ^ u ^ f; register slot b holds global k-bytes [(2h+b)*16,+16).
  int u = (l31 >> 4) & 1;
  int f = (l31 >> 1) & 3;
  int cs0 = (h << 1) ^ u ^ f;
  int offA[2], offB[2];
#pragma unroll
  for (int i = 0; i < 2; i++) {
    int rowa = rw * 64 + i * 32 + l31;
    offA[i] = rowa * 64 + cs0 * 16;
    int rowb = cw * 64 + i * 32 + l31;
    offB[i] = 8192 + rowb * 64 + cs0 * 16;
  }

  // staging base pointers: slot s = it*256+t -> row = it*64 + (t>>2), cs = t&3;
  // src piece = cs ^ f(row) ^ u(row) = (t&3) ^ ((t>>3)&3) ^ ((t>>6)&1)  (it-invariant)
  int srow = t >> 2;
  int ssrc = (t & 3) ^ ((t >> 3) & 3) ^ ((t >> 6) & 1);
  const unsigned char* pA = X + (size_t)(r0 + srow) * D + ssrc * 16;
  const unsigned char* pB = Y + (size_t)(c0 + srow) * D + ssrc * 16;

  f32x16 acc[2][2];
#pragma unroll
  for (int i = 0; i < 2; i++)
#pragma unroll
    for (int j = 0; j < 2; j++)
#pragma unroll
      for (int r = 0; r < 16; r++) acc[i][j][r] = 0.0f;

  stage_chunk(pA, pB, lds, t, 0);

  SG_ROUND(0) SG_ROUND(1) SG_ROUND(2) SG_ROUND(3)
  SG_ROUND(4) SG_ROUND(5) SG_ROUND(6) SG_ROUND(7)

  __syncthreads(); // dbuf dead; reuse as reduction scratch

  if (smode) {
    // ---- row + col sums of exp2(scale*g); fixed reference (fits fp32) ----
    float csum[2] = {0.0f, 0.0f};
#pragma unroll
    for (int i = 0; i < 2; i++) {
      float rsum[16];
#pragma unroll
      for (int reg = 0; reg < 16; reg++) rsum[reg] = 0.0f;
#pragma unroll
      for (int j = 0; j < 2; j++)
#pragma unroll
        for (int reg = 0; reg < 16; reg++) {
          float e = __builtin_amdgcn_exp2f(acc[i][j][reg] * scale);
          rsum[reg] += e;
          csum[j] += e;
        }
      // row-sum: reduce across the 32 lanes of this k/row-half (bit5 preserved)
#pragma unroll
      for (int reg = 0; reg < 16; reg++) {
#pragma unroll
        for (int off = 1; off < 32; off <<= 1) rsum[reg] += __shfl_xor(rsum[reg], off);
      }
      if (l31 == 0) {
#pragma unroll
        for (int reg = 0; reg < 16; reg++) {
          int rloc = (reg & 3) + 8 * (reg >> 2) + 4 * h;
          redB[cw][rw * 64 + i * 32 + rloc] = rsum[reg];
        }
      }
    }
    // col-sum: add the other row-half, then one lane-half writes
#pragma unroll
    for (int j = 0; j < 2; j++) {
      csum[j] += __shfl_xor(csum[j], 32);
      if (h == 0) redA[rw][cw * 64 + j * 32 + l31] = csum[j];
    }
    __syncthreads();
    if (t < BM) {
      colS[(size_t)(r0 >> 7) * N + c0 + t] = redA[0][t] + redA[1][t];
      rowS[(size_t)(c0 >> 7) * N + r0 + t] = redB[0][t] + redB[1][t];
    }
  } else {
    // ---- Gram: row max (strip a), diag-masked; col max = row max of strip b ----
#pragma unroll
    for (int i = 0; i < 2; i++) {
      float rmax[16];
#pragma unroll
      for (int reg = 0; reg < 16; reg++) {
        int rloc = (reg & 3) + 8 * (reg >> 2) + 4 * h;
        int rr = rw * 64 + i * 32 + rloc;
        float v = -3.0e38f;
#pragma unroll
        for (int j = 0; j < 2; j++) {
          float x = acc[i][j][reg];
          int cc = cw * 64 + j * 32 + l31;
          if (diagb && cc == rr) x = -3.0e38f;
          v = fmaxf(v, x);
        }
        rmax[reg] = v;
      }
#pragma unroll
      for (int reg = 0; reg < 16; reg++) {
#pragma unroll
        for (int off = 1; off < 32; off <<= 1) rmax[reg] = fmaxf(rmax[reg], __shfl_xor(rmax[reg], off));
      }
      if (l31 == 0) {
#pragma unroll
        for (int reg = 0; reg < 16; reg++) {
          int rloc = (reg & 3) + 8 * (reg >> 2) + 4 * h;
          redA[cw][rw * 64 + i * 32 + rloc] = rmax[reg];
        }
      }
    }
    if (!diagb) {
#pragma unroll
      for (int j = 0; j < 2; j++) {
        float m = -3.0e38f;
#pragma unroll
        for (int i = 0; i < 2; i++)
#pragma unroll
          for (int reg = 0; reg < 16; reg++) m = fmaxf(m, acc[i][j][reg]);
        m = fmaxf(m, __shfl_xor(m, 32));
        if (h == 0) redB[rw][cw * 64 + j * 32 + l31] = m;
      }
    }
    __syncthreads();
    if (t < BM) {
      partG[((size_t)(gg * NSTRIP + gb)) * N + r0 + t] = fmaxf(redA[0][t], redA[1][t]);
      if (!diagb)
        partG[((size_t)(gg * NSTRIP + ga)) * N + c0 + t] = fmaxf(redB[0][t], redB[1][t]);
    }
  }
}

// ---------------- per-row combine of partials -> atomic scalar ----------------
__global__ __launch_bounds__(256) void combine_kernel(
    const float* __restrict__ diag,
    const float* __restrict__ rowS, const float* __restrict__ colS,
    const float* __restrict__ partG, float* __restrict__ out) {
  int t = threadIdx.x;
  int l = t & 63;
  int w = t >> 6;
  int i = blockIdx.x * 64 + l;

  float sR = 0.0f, sC = 0.0f, g1 = -3.0e38f, g2 = -3.0e38f;
#pragma unroll
  for (int s = 0; s < 16; s++) {
    int strip = w * 16 + s;
    sR += rowS[(size_t)strip * N + i];
    sC += colS[(size_t)strip * N + i];
    g1 = fmaxf(g1, partG[(size_t)strip * N + i]);
    g2 = fmaxf(g2, partG[(size_t)(NSTRIP + strip) * N + i]);
  }
  __shared__ float red[4][4][64];
  red[0][w][l] = sR; red[1][w][l] = sC; red[2][w][l] = g1; red[3][w][l] = g2;
  __syncthreads();
  if (w == 0) {
    sR = red[0][0][l] + red[0][1][l] + red[0][2][l] + red[0][3][l];
    sC = red[1][0][l] + red[1][1][l] + red[1][2][l] + red[1][3][l];
    g1 = fmaxf(fmaxf(red[2][0][l], red[2][1][l]), fmaxf(red[2][2][l], red[2][3][l]));
    g2 = fmaxf(fmaxf(red[3][0][l], red[3][1][l]), fmaxf(red[3][2][l], red[3][3][l]));
    float dv = diag[i] * 25.0f;
    float a12 = logf(sR) - dv;
    float a21 = logf(sC) - dv;
    float k1 = logf(sqrtf(fmaxf(2.0f - 2.0f * g1, 0.0f)) + 1e-9f);
    float k2 = logf(sqrtf(fmaxf(2.0f - 2.0f * g2, 0.0f)) + 1e-9f);
    float c = 0.5f * (a12 + a21) / (float)N - 0.1f * 0.5f * (k1 + k2) / (float)N;
#pragma unroll
    for (int off = 1; off < 64; off <<= 1) c += __shfl_xor(c, off);
    if (l == 0) atomicAdd(out, c); // device-scope, out zeroed by norm_kernel
  }
}

extern "C" void kernel_launch(void* const* d_in, const int* in_sizes, int n_in,
                              void* d_out, int out_size, void* d_ws, size_t ws_size,
                              hipStream_t stream) {
  const float* z1 = (const float*)d_in[0];
  const float* z2 = (const float*)d_in[1];
  char* w = (char*)d_ws;
  unsigned char* q1 = (unsigned char*)w; w += (size_t)N * D;
  unsigned char* q2 = (unsigned char*)w; w += (size_t)N * D;
  float* diag = (float*)w;   w += (size_t)N * sizeof(float);
  float* rowS = (float*)w;   w += (size_t)NSTRIP * N * sizeof(float);
  float* colS = (float*)w;   w += (size_t)NSTRIP * N * sizeof(float);
  float* partG = (float*)w;  w += (size_t)2 * NSTRIP * N * sizeof(float);
  float* out = (float*)d_out;

  norm_kernel<<<N / 4, 256, 0, stream>>>(z1, z2, q1, q2, diag, out);
  sg_kernel<<<SG_BLOCKS, 256, 0, stream>>>(q1, q2, rowS, colS, partG);
  combine_kernel<<<N / 64, 256, 0, stream>>>(diag, rowS, colS, partG, out);
}